// Round 8
// baseline (568.512 us; speedup 1.0000x reference)
//
#include <hip/hip_runtime.h>
#include <stdint.h>

// VQVAE quantise, fp32 in/out.
// R8: barrier-free redesign. R2-R7 invariant: lockstep-barriered waves pay
// ~20k idle cy/iter that occupancy/barrier-flavor/swizzle/delivery/tile-size
// changes never removed (R7 additionally spilled: launch_bounds(512,2) caps
// 128 VGPR, live set ~190 -> +215MB scratch writes). Fix: drop LDS staging
// entirely -> zero __syncthreads in the whole kernel. Each wave loads its
// B-fragments straight from global into regs (lane (l15,quad) reads
// dict[s0+l15][kk*32+quad*8..+8]; wave consumes full 64B lines), converts
// privately (16x redundant, ~20us chip VALU - cheap vs the stalls), and
// scans 16 rows x 1024 codes independently: loads(ch+1) || MFMA(ch) ||
// NT-zero stores, hidden by 16 waves/CU (4 blk x 4 waves, live set ~120
// VGPR under the 128 cap of launch_bounds(256,4)).
// Grid 1024 = squad(4) x btile(4) x c(64). Per-wave argmin closes with a
// shfl_xor butterfly (exact first-occurrence ties); 4 squad candidates
// parked in cw_out cells, combined by finalize (unchanged from R7).
// Per-element distance math / split8 / MFMA order unchanged; dsq partial
// grouping is per-quad (last-ulp regrouping, same as R6's regroup: passed).

#define B_SZ 256
#define C_SZ 64
#define E_SZ 128
#define S_SZ 4096
#define CW   8192
#define SPB  1024          // codes per block (one squad)
#define NCH  (SPB / 16)    // 64 chunk iterations per wave

typedef __attribute__((ext_vector_type(4))) float    float4a;
typedef __attribute__((ext_vector_type(8))) _Float16 half8;

__device__ __forceinline__ void split8(float4a f0, float4a f1, half8& hi, half8& lo) {
    #pragma unroll
    for (int j = 0; j < 4; ++j) {
        _Float16 h0 = (_Float16)f0[j];
        hi[j]     = h0;
        lo[j]     = (_Float16)(f0[j] - (float)h0);
        _Float16 h1 = (_Float16)f1[j];
        hi[4 + j] = h1;
        lo[4 + j] = (_Float16)(f1[j] - (float)h1);
    }
}

// grid 1024 = (squad 0..3) x (btile 0..3) x (c 0..63), block 256 = 4 waves.
// Wave w owns x-rows [btile*64 + w*16, +16) vs codes [squad*1024, +1024).
__global__ __launch_bounds__(256, 4) void argmin_mfma(
    const float* __restrict__ x,
    const float* __restrict__ dict,
    float* __restrict__ cw_out,
    float* __restrict__ oh)
{
    const int tid   = threadIdx.x;
    const int lane  = tid & 63;
    const int quad  = lane >> 4;
    const int l15   = lane & 15;
    const int w     = tid >> 6;
    const int c     = blockIdx.x & 63;
    const int btile = (blockIdx.x >> 6) & 3;
    const int squad = blockIdx.x >> 8;
    const int sbase = squad * SPB;
    const int rowbase = btile * 64 + w * 16;

    // ---- runtime layout probes, packed to 2 regs: (row,col) of (lane,reg r) ----
    int mpack = 0, npack = 0;
    {
        half8 ones, enc;
        #pragma unroll
        for (int j = 0; j < 8; ++j) { ones[j] = (_Float16)1.0f; enc[j] = (_Float16)(float)l15; }
        float4a z = {0.f, 0.f, 0.f, 0.f};
        float4a pr = __builtin_amdgcn_mfma_f32_16x16x32_f16(enc, ones, z, 0, 0, 0);
        float4a pc = __builtin_amdgcn_mfma_f32_16x16x32_f16(ones, enc, z, 0, 0, 0);
        #pragma unroll
        for (int r = 0; r < 4; ++r) {
            mpack |= ((int)(pr[r] * 0.03125f + 0.5f)) << (8 * r);
            npack |= ((int)(pc[r] * 0.03125f + 0.5f)) << (8 * r);
        }
    }

    // ---- A fragments (16 rows/wave): loader believes A[m=l15][k=kk*32+quad*8+j] ----
    half8 ah[4], al[4];
    {
        const float* xr = x + (size_t)(rowbase + l15) * CW + c * E_SZ;
        #pragma unroll
        for (int kk = 0; kk < 4; ++kk) {
            float4a f0 = *reinterpret_cast<const float4a*>(xr + kk * 32 + quad * 8);
            float4a f1 = *reinterpret_cast<const float4a*>(xr + kk * 32 + quad * 8 + 4);
            split8(f0, f1, ah[kk], al[kk]);
        }
    }

    // ---- lane's dict pointer: B-loader believes col=l15 -> row sbase+ch*16+l15 ----
    const float* dl = dict + ((size_t)c * S_SZ + sbase + l15) * E_SZ + quad * 8;

    float bestv[4];
    int   besti[4];
    #pragma unroll
    for (int r = 0; r < 4; ++r) { bestv[r] = 3.4e38f; besti[r] = 0; }

    // ---- prologue: load + convert chunk 0 ----
    float4a pf[8];
    #pragma unroll
    for (int kk = 0; kk < 4; ++kk) {
        pf[2 * kk]     = *reinterpret_cast<const float4a*>(dl + kk * 32);
        pf[2 * kk + 1] = *reinterpret_cast<const float4a*>(dl + kk * 32 + 4);
    }
    half8 bhf[4], blf[4];
    float dqf;
    {
        float dp = 0.f;
        #pragma unroll
        for (int kk = 0; kk < 4; ++kk) {
            split8(pf[2 * kk], pf[2 * kk + 1], bhf[kk], blf[kk]);
            #pragma unroll
            for (int j = 0; j < 4; ++j) {
                dp = fmaf(pf[2 * kk][j], pf[2 * kk][j], dp);
                dp = fmaf(pf[2 * kk + 1][j], pf[2 * kk + 1][j], dp);
            }
        }
        float t = dp + __shfl_xor(dp, 16, 64);
        dqf = t + __shfl_xor(t, 32, 64);     // full |d|^2 for code s0+l15, all lanes
    }

    // ---- main loop: NO barriers; loads(ch+1) || zero-store || MFMA/epi(ch) ----
    for (int ch = 0; ch < NCH; ++ch) {
        if (ch + 1 < NCH) {
            const float* dn = dl + (size_t)(ch + 1) * 16 * E_SZ;
            #pragma unroll
            for (int kk = 0; kk < 4; ++kk) {
                pf[2 * kk]     = *reinterpret_cast<const float4a*>(dn + kk * 32);
                pf[2 * kk + 1] = *reinterpret_cast<const float4a*>(dn + kk * 32 + 4);
            }
        }

        // zero 1KB of this wave's one-hot slice (issued AFTER the loads, so
        // load-waits never force store retirement; stores drain lazily)
        {
            const int zrow = rowbase + (ch >> 2);
            float* zb = oh + ((size_t)zrow * C_SZ + c) * S_SZ + sbase + (ch & 3) * 256;
            float4a zz = {0.f, 0.f, 0.f, 0.f};
            __builtin_nontemporal_store(zz, reinterpret_cast<float4a*>(zb) + lane);
        }

        // MFMA on chunk ch (registers only)
        float4a acc = {0.f, 0.f, 0.f, 0.f};
        #pragma unroll
        for (int kk = 0; kk < 4; ++kk) {
            acc = __builtin_amdgcn_mfma_f32_16x16x32_f16(ah[kk], bhf[kk], acc, 0, 0, 0);
            acc = __builtin_amdgcn_mfma_f32_16x16x32_f16(ah[kk], blf[kk], acc, 0, 0, 0);
            acc = __builtin_amdgcn_mfma_f32_16x16x32_f16(al[kk], bhf[kk], acc, 0, 0, 0);
        }

        // epilogue: dist = d_sq - 2*cross (x_sq const per (b,c): argmin-invariant)
        #pragma unroll
        for (int r = 0; r < 4; ++r) {
            const int na = (npack >> (8 * r)) & 15;        // true col attribution
            float dsq = __shfl(dqf, (lane & 48) | na, 64); // dsq lives at l15==na
            int sg = sbase + ch * 16 + na;
            float dist = dsq - 2.0f * acc[r];
            if (dist < bestv[r]) { bestv[r] = dist; besti[r] = sg; }
        }

        // convert prefetched chunk into bhf/blf + next dqf
        if (ch + 1 < NCH) {
            float dp = 0.f;
            #pragma unroll
            for (int kk = 0; kk < 4; ++kk) {
                split8(pf[2 * kk], pf[2 * kk + 1], bhf[kk], blf[kk]);
                #pragma unroll
                for (int j = 0; j < 4; ++j) {
                    dp = fmaf(pf[2 * kk][j], pf[2 * kk][j], dp);
                    dp = fmaf(pf[2 * kk + 1][j], pf[2 * kk + 1][j], dp);
                }
            }
            float t = dp + __shfl_xor(dp, 16, 64);
            dqf = t + __shfl_xor(t, 32, 64);
        }
    }

    // ---- cross-col combine: butterfly over the 16 lanes of each quad-group
    //      (they share the same 4 output rows; cols partition s mod 16).
    //      Tie rule (v==bv -> smaller s) => exact global first-occurrence. ----
    #pragma unroll
    for (int m = 1; m < 16; m <<= 1) {
        #pragma unroll
        for (int r = 0; r < 4; ++r) {
            float ov = __shfl_xor(bestv[r], m, 64);
            int   oi = __shfl_xor(besti[r], m, 64);
            if (ov < bestv[r] || (ov == bestv[r] && oi < besti[r])) {
                bestv[r] = ov; besti[r] = oi;
            }
        }
    }

    // ---- park (dist, idx) per row in the cw_out cell finalize overwrites;
    //      squad slots (2 floats) disjoint. Kernel end drains NT stores. ----
    if (l15 == 0) {
        #pragma unroll
        for (int r = 0; r < 4; ++r) {
            const int row = rowbase + ((mpack >> (8 * r)) & 15);
            float* cp = cw_out + (size_t)row * CW + c * E_SZ + squad * 2;
            cp[0] = bestv[r];
            cp[1] = __int_as_float(besti[r]);
        }
    }
}

// grid 256 = (btile, c), 256 threads: combine 4 s-quarter candidates per row,
// write the one-hot 1.0, gather cw_embed (overwrites the candidate slab).
__global__ __launch_bounds__(256) void finalize(
    const float* __restrict__ dict,
    float* __restrict__ cw_out,
    float* __restrict__ oh)
{
    __shared__ int fid[64];
    const int c     = blockIdx.x & 63;
    const int btile = blockIdx.x >> 6;
    const int tid   = threadIdx.x;

    if (tid < 64) {
        const int row = btile * 64 + tid;
        const float* cp = cw_out + (size_t)row * CW + c * E_SZ;
        float bv = cp[0]; int bi = __float_as_int(cp[1]);
        #pragma unroll
        for (int k = 1; k < 4; ++k) {
            float v = cp[2 * k];
            // squads are s-ordered: strict < preserves global first-occurrence
            if (v < bv) { bv = v; bi = __float_as_int(cp[2 * k + 1]); }
        }
        fid[tid] = bi;
        oh[((size_t)row * C_SZ + c) * S_SZ + bi] = 1.0f;
    }
    __syncthreads();

    // gather: 64 rows x 32 float4, 4 threads/row x 8 float4 each
    const int row = tid >> 2, q = tid & 3;
    const int bi = fid[row];
    const float4a* src = reinterpret_cast<const float4a*>(
        dict + ((size_t)c * S_SZ + bi) * E_SZ) + q * 8;
    float4a* dst = reinterpret_cast<float4a*>(
        cw_out + (size_t)(btile * 64 + row) * CW + c * E_SZ) + q * 8;
    #pragma unroll
    for (int j = 0; j < 8; ++j) dst[j] = src[j];
}

extern "C" void kernel_launch(void* const* d_in, const int* in_sizes, int n_in,
                              void* d_out, int out_size, void* d_ws, size_t ws_size,
                              hipStream_t stream) {
    const float* x    = (const float*)d_in[0];
    const float* dict = (const float*)d_in[1];
    float* out = (float*)d_out;
    float* oh  = out + (size_t)B_SZ * CW;

    argmin_mfma<<<dim3(1024), dim3(256), 0, stream>>>(x, dict, out, oh);
    finalize<<<dim3(256), dim3(256), 0, stream>>>(dict, out, oh);
}

// Round 9
// 445.432 us; speedup vs baseline: 1.2763x; 1.2763x over previous
//
#include <hip/hip_runtime.h>
#include <stdint.h>

// VQVAE quantise, fp32 in/out.
// R9: R6 (best measured: argmin 171us) with ONE isolated change: the fused
// one-hot zero-stores are PLAIN CACHED stores, not nontemporal. Theory: NT
// stores bypass L2 so vmcnt retirement needs HBM-level ack (~2-4k cy); the
// per-iter __syncthreads drains vmcnt(0), so all 16 iterations eat a write
// ack round-trip in lockstep (the R2-R8 invariant ~20k idle cy/iter).
// Plain stores ack at L2 (~300 cy) and write back asynchronously — the
// harness's own fillBuffer achieves 6.4 TB/s exactly this way.
// Everything else (grid 256 = squad x c, delivery-optimal blocking, LDS
// double-buffer + swizzle, prefetch-first, plain __syncthreads, candidate
// parking + finalize, distance math, tie-break) is byte-identical to R6.

#define B_SZ 256
#define C_SZ 64
#define E_SZ 128
#define S_SZ 4096
#define CW   8192
#define TS   64     // dict rows staged per iter
#define SPB  1024   // S-range per block
#define LDB  128    // LDS B-row stride in f16 (swizzled)

typedef __attribute__((ext_vector_type(4))) float    float4a;
typedef __attribute__((ext_vector_type(8))) _Float16 half8;

__device__ __forceinline__ int swz(int row, int cf16) {
    return row * LDB + (cf16 ^ ((row & 7) << 3));
}

__device__ __forceinline__ void split8(float4a f0, float4a f1, half8& hi, half8& lo) {
    #pragma unroll
    for (int j = 0; j < 4; ++j) {
        _Float16 h0 = (_Float16)f0[j];
        hi[j]     = h0;
        lo[j]     = (_Float16)(f0[j] - (float)h0);
        _Float16 h1 = (_Float16)f1[j];
        hi[4 + j] = h1;
        lo[4 + j] = (_Float16)(f1[j] - (float)h1);
    }
}

// grid 256 = (squad 0..3) x (c 0..63), block 512 = 8 waves (mq 0..3, nh 0..1).
__global__ __launch_bounds__(512, 2) void argmin_mfma(
    const float* __restrict__ x,
    const float* __restrict__ dict,
    float* __restrict__ cw_out,
    float* __restrict__ oh)
{
    __shared__ __attribute__((aligned(16))) _Float16 bh[2][TS * LDB];  // 2x16 KB
    __shared__ __attribute__((aligned(16))) _Float16 bl[2][TS * LDB];  // 2x16 KB
    __shared__ __attribute__((aligned(16))) float dsqp[2][TS][8];      // 4 KB
    // final reduction tables aliased onto staging LDS (used after the loop)
    float* rv = reinterpret_cast<float*>(bh);   // 32 cols x 256 rows = 32 KB
    int*   ri = reinterpret_cast<int*>(bl);     // 32 KB

    const int tid   = threadIdx.x;
    const int lane  = tid & 63;
    const int quad  = lane >> 4;
    const int l15   = lane & 15;
    const int wid   = tid >> 6;
    const int mq    = wid & 3;
    const int nh    = wid >> 2;
    const int c     = blockIdx.x & 63;
    const int squad = blockIdx.x >> 6;
    const int sbase = squad * SPB;

    // ---- runtime layout probes: true (row, col) of each (lane, reg) ----
    int m_attr[4], n_attr[4];
    {
        half8 ones, enc;
        #pragma unroll
        for (int j = 0; j < 8; ++j) { ones[j] = (_Float16)1.0f; enc[j] = (_Float16)(float)l15; }
        float4a z = {0.f, 0.f, 0.f, 0.f};
        float4a pr = __builtin_amdgcn_mfma_f32_16x16x32_f16(enc, ones, z, 0, 0, 0);
        float4a pc = __builtin_amdgcn_mfma_f32_16x16x32_f16(ones, enc, z, 0, 0, 0);
        #pragma unroll
        for (int r = 0; r < 4; ++r) {
            m_attr[r] = (int)(pr[r] * 0.03125f + 0.5f);   // row feeding this element
            n_attr[r] = (int)(pc[r] * 0.03125f + 0.5f);   // col feeding this element
        }
    }

    // ---- A fragments (regs, whole kernel): wave mq owns rows [mq*64, mq*64+64) ----
    half8 ah[4][4], al[4][4];
    #pragma unroll
    for (int mi = 0; mi < 4; ++mi) {
        int b = mq * 64 + mi * 16 + l15;
        const float* xr = x + (size_t)b * CW + c * E_SZ;
        #pragma unroll
        for (int kk = 0; kk < 4; ++kk) {
            float4a f0 = *reinterpret_cast<const float4a*>(xr + kk * 32 + quad * 8);
            float4a f1 = *reinterpret_cast<const float4a*>(xr + kk * 32 + quad * 8 + 4);
            split8(f0, f1, ah[mi][kk], al[mi][kk]);
        }
    }

    // ---- staging coords: 64 rows x 128 f32, 16 f32/thread ----
    const int srow = tid >> 3;
    const int kq   = (tid & 7) * 16;
    const int q8   = tid & 7;
    const float* drow = dict + ((size_t)c * S_SZ + sbase + srow) * E_SZ + kq;

    // ---- prologue: load + convert tile 0 into buffer 0 ----
    float4a pf[4];
    #pragma unroll
    for (int ck = 0; ck < 4; ++ck)
        pf[ck] = *reinterpret_cast<const float4a*>(drow + ck * 4);
    {
        float dp = 0.f;
        #pragma unroll
        for (int ck = 0; ck < 2; ++ck) {
            half8 h, l;
            split8(pf[2 * ck], pf[2 * ck + 1], h, l);
            #pragma unroll
            for (int j = 0; j < 4; ++j) {
                dp = fmaf(pf[2 * ck][j], pf[2 * ck][j], dp);
                dp = fmaf(pf[2 * ck + 1][j], pf[2 * ck + 1][j], dp);
            }
            *reinterpret_cast<half8*>(&bh[0][swz(srow, kq + ck * 8)]) = h;
            *reinterpret_cast<half8*>(&bl[0][swz(srow, kq + ck * 8)]) = l;
        }
        dsqp[0][srow][q8] = dp;
    }

    float bestv[16];
    int   besti[16];
    #pragma unroll
    for (int i = 0; i < 16; ++i) { bestv[i] = 3.4e38f; besti[i] = 0; }

    __syncthreads();

    int cur = 0;
    for (int it = 0; it < 16; ++it) {
        // ---- issue next tile's global loads FIRST (oldest in vmcnt queue) ----
        if (it + 1 < 16) {
            const float* dr = drow + (size_t)(it + 1) * (TS * E_SZ);
            #pragma unroll
            for (int ck = 0; ck < 4; ++ck)
                pf[ck] = *reinterpret_cast<const float4a*>(dr + ck * 4);
        }

        // ---- zero 16 of the 256 one-hot row-slices: PLAIN cached stores
        //      (ack at L2, write back async — the 6.4 TB/s fill path) ----
        {
            const int zrow = it * 16 + (tid >> 5);
            const int t5   = tid & 31;
            float* zb = oh + ((size_t)zrow * C_SZ + c) * S_SZ + sbase;
            float4a zz = {0.f, 0.f, 0.f, 0.f};
            #pragma unroll
            for (int j = 0; j < 8; ++j)
                reinterpret_cast<float4a*>(zb)[t5 + j * 32] = zz;
        }

        // ---- MFMA phase on buf[cur]: 96 MFMAs/wave ----
        const _Float16* bhc = bh[cur];
        const _Float16* blc = bl[cur];
        float4a acc[4][2] = {{{0.f,0.f,0.f,0.f},{0.f,0.f,0.f,0.f}},
                             {{0.f,0.f,0.f,0.f},{0.f,0.f,0.f,0.f}},
                             {{0.f,0.f,0.f,0.f},{0.f,0.f,0.f,0.f}},
                             {{0.f,0.f,0.f,0.f},{0.f,0.f,0.f,0.f}}};
        __builtin_amdgcn_s_setprio(1);
        #pragma unroll
        for (int kk = 0; kk < 4; ++kk) {
            half8 bhf[2], blf[2];
            #pragma unroll
            for (int ni = 0; ni < 2; ++ni) {
                const int sl = nh * 32 + ni * 16 + l15;   // loader believes col = l15
                bhf[ni] = *reinterpret_cast<const half8*>(bhc + swz(sl, kk * 32 + quad * 8));
                blf[ni] = *reinterpret_cast<const half8*>(blc + swz(sl, kk * 32 + quad * 8));
            }
            #pragma unroll
            for (int mi = 0; mi < 4; ++mi)
                #pragma unroll
                for (int ni = 0; ni < 2; ++ni) {
                    acc[mi][ni] = __builtin_amdgcn_mfma_f32_16x16x32_f16(
                        ah[mi][kk], bhf[ni], acc[mi][ni], 0, 0, 0);
                    acc[mi][ni] = __builtin_amdgcn_mfma_f32_16x16x32_f16(
                        ah[mi][kk], blf[ni], acc[mi][ni], 0, 0, 0);
                    acc[mi][ni] = __builtin_amdgcn_mfma_f32_16x16x32_f16(
                        al[mi][kk], bhf[ni], acc[mi][ni], 0, 0, 0);
                }
        }
        __builtin_amdgcn_s_setprio(0);

        // ---- epilogue: dist = d_sq - 2*cross (x_sq const per (b,c): argmin-invariant) ----
        #pragma unroll
        for (int ni = 0; ni < 2; ++ni)
            #pragma unroll
            for (int r = 0; r < 4; ++r) {
                const int sl = nh * 32 + ni * 16 + n_attr[r];   // true col attribution
                float4a qa = *reinterpret_cast<const float4a*>(&dsqp[cur][sl][0]);
                float4a qb = *reinterpret_cast<const float4a*>(&dsqp[cur][sl][4]);
                float dsq = ((qa[0] + qa[1]) + (qa[2] + qa[3]))
                          + ((qb[0] + qb[1]) + (qb[2] + qb[3]));
                int sg = sbase + it * TS + sl;
                #pragma unroll
                for (int mi = 0; mi < 4; ++mi) {
                    float dist = dsq - 2.0f * acc[mi][ni][r];
                    int slot = mi * 4 + r;
                    if (dist < bestv[slot]) { bestv[slot] = dist; besti[slot] = sg; }
                }
            }

        // ---- convert prefetched tile into buf[cur^1] ----
        if (it + 1 < 16) {
            const int nb = cur ^ 1;
            float dp = 0.f;
            #pragma unroll
            for (int ck = 0; ck < 2; ++ck) {
                half8 h, l;
                split8(pf[2 * ck], pf[2 * ck + 1], h, l);
                #pragma unroll
                for (int j = 0; j < 4; ++j) {
                    dp = fmaf(pf[2 * ck][j], pf[2 * ck][j], dp);
                    dp = fmaf(pf[2 * ck + 1][j], pf[2 * ck + 1][j], dp);
                }
                *reinterpret_cast<half8*>(&bh[nb][swz(srow, kq + ck * 8)]) = h;
                *reinterpret_cast<half8*>(&bl[nb][swz(srow, kq + ck * 8)]) = l;
            }
            dsqp[nb][srow][q8] = dp;
        }
        __syncthreads();
        cur ^= 1;
    }

    // loop-end barrier: all LDS reads done (alias rv/ri); this block's
    // s-quarter of all 256 one-hot rows is zeroed.

    // ---- dump: bijective (row 0..255) x (col 0..31) scatter, transposed
    //      (rv[col*256+row]) so the scan below is bank-conflict-free ----
    #pragma unroll
    for (int mi = 0; mi < 4; ++mi)
        #pragma unroll
        for (int r = 0; r < 4; ++r) {
            int row = mq * 64 + mi * 16 + m_attr[r];
            int col = nh * 16 + n_attr[r];
            rv[col * 256 + row] = bestv[mi * 4 + r];
            ri[col * 256 + row] = besti[mi * 4 + r];
        }
    __syncthreads();

    if (tid < 256) {
        float bv = 3.4e38f; int bi = 0x7fffffff;
        #pragma unroll 4
        for (int j = 0; j < 32; ++j) {
            float v = rv[j * 256 + tid];
            int   i = ri[j * 256 + tid];
            if (v < bv || (v == bv && i < bi)) { bv = v; bi = i; }  // first-occurrence tie
        }
        // park (dist, idx) in the cw_out cell finalize reads-then-overwrites;
        // squad slots (2 floats each) are disjoint.
        float* cp = cw_out + (size_t)tid * CW + c * E_SZ + squad * 2;
        cp[0] = bv;
        cp[1] = __int_as_float(bi);
    }
    // kernel end drains all zero-stores before finalize runs
}

// grid 256 = (btile, c), 256 threads: combine 4 s-quarter candidates per row,
// write the one-hot 1.0, gather cw_embed (overwrites the candidate slab).
__global__ __launch_bounds__(256) void finalize(
    const float* __restrict__ dict,
    float* __restrict__ cw_out,
    float* __restrict__ oh)
{
    __shared__ int fid[64];
    const int c     = blockIdx.x & 63;
    const int btile = blockIdx.x >> 6;
    const int tid   = threadIdx.x;

    if (tid < 64) {
        const int row = btile * 64 + tid;
        const float* cp = cw_out + (size_t)row * CW + c * E_SZ;
        float bv = cp[0]; int bi = __float_as_int(cp[1]);
        #pragma unroll
        for (int k = 1; k < 4; ++k) {
            float v = cp[2 * k];
            // squads are s-ordered: strict < preserves global first-occurrence
            if (v < bv) { bv = v; bi = __float_as_int(cp[2 * k + 1]); }
        }
        fid[tid] = bi;
        oh[((size_t)row * C_SZ + c) * S_SZ + bi] = 1.0f;
    }
    __syncthreads();

    // gather: 64 rows x 32 float4, 4 threads/row x 8 float4 each
    const int row = tid >> 2, q = tid & 3;
    const int bi = fid[row];
    const float4a* src = reinterpret_cast<const float4a*>(
        dict + ((size_t)c * S_SZ + bi) * E_SZ) + q * 8;
    float4a* dst = reinterpret_cast<float4a*>(
        cw_out + (size_t)(btile * 64 + row) * CW + c * E_SZ) + q * 8;
    #pragma unroll
    for (int j = 0; j < 8; ++j) dst[j] = src[j];
}

extern "C" void kernel_launch(void* const* d_in, const int* in_sizes, int n_in,
                              void* d_out, int out_size, void* d_ws, size_t ws_size,
                              hipStream_t stream) {
    const float* x    = (const float*)d_in[0];
    const float* dict = (const float*)d_in[1];
    float* out = (float*)d_out;
    float* oh  = out + (size_t)B_SZ * CW;

    argmin_mfma<<<dim3(256), dim3(512), 0, stream>>>(x, dict, out, oh);
    finalize<<<dim3(256), dim3(256), 0, stream>>>(dict, out, oh);
}

// Round 10
// 407.561 us; speedup vs baseline: 1.3949x; 1.0929x over previous
//
#include <hip/hip_runtime.h>
#include <stdint.h>

// VQVAE quantise, fp32 in/out.
// R10: staging-path fix (guide Common-mistake #1). R6 staged via
// global->VGPR->split8->ds_write: VGPR round-trip + convert on the serial
// staging leg. Now: raw f32 dict tile staged via global_load_lds width=16
// (4 per thread, no VGPR round-trip); conversion moved into the consume
// phase (each wave ds_reads its f32 fragments, split8 in-register);
// |d|^2 computed per-row from per-quad partials + 2 shfl_xor (dsqp LDS
// pass and its conflicted epilogue reads deleted). LDS granule XOR-swizzle
// (16B, g ^= row&7) applied BOTH sides: pre-swizzled per-lane global source
// (global_load_lds writes linearly, m104/m173 rule) + swizzled ds_read.
// s_setprio dropped (m190: null/negative on lockstep waves).
// Rest identical to R6 (best measured 171us): grid 256 = squad x c,
// delivery-optimal blocking, NT one-hot zero-stores fused, plain
// __syncthreads, candidate parking in cw_out + finalize, MFMA order,
// first-occurrence tie-break.

#define B_SZ 256
#define C_SZ 64
#define E_SZ 128
#define S_SZ 4096
#define CW   8192
#define TS   64     // dict rows staged per iter
#define SPB  1024   // S-range per block

typedef __attribute__((ext_vector_type(4))) float    float4a;
typedef __attribute__((ext_vector_type(8))) _Float16 half8;

typedef __attribute__((address_space(1))) const uint32_t gu32;
typedef __attribute__((address_space(3))) uint32_t       lu32;

__device__ __forceinline__ void split8(float4a f0, float4a f1, half8& hi, half8& lo) {
    #pragma unroll
    for (int j = 0; j < 4; ++j) {
        _Float16 h0 = (_Float16)f0[j];
        hi[j]     = h0;
        lo[j]     = (_Float16)(f0[j] - (float)h0);
        _Float16 h1 = (_Float16)f1[j];
        hi[4 + j] = h1;
        lo[4 + j] = (_Float16)(f1[j] - (float)h1);
    }
}

// grid 256 = (squad 0..3) x (c 0..63), block 512 = 8 waves (mq 0..3, nh 0..1).
__global__ __launch_bounds__(512, 2) void argmin_mfma(
    const float* __restrict__ x,
    const float* __restrict__ dict,
    float* __restrict__ cw_out,
    float* __restrict__ oh)
{
    // raw f32 dict tiles, double buffered; row stride 128 f32 = 512 B;
    // 16B granules XOR-swizzled by (row&7). 2 x 32 KB.
    __shared__ __attribute__((aligned(16))) float df[2][TS * E_SZ];
    // final reduction tables aliased onto staging LDS (used after the loop)
    float* rv = reinterpret_cast<float*>(df[0]);   // 32 cols x 256 rows = 32 KB
    int*   ri = reinterpret_cast<int*>(df[1]);     // 32 KB

    const int tid   = threadIdx.x;
    const int lane  = tid & 63;
    const int quad  = lane >> 4;
    const int l15   = lane & 15;
    const int wid   = tid >> 6;
    const int mq    = wid & 3;
    const int nh    = wid >> 2;
    const int c     = blockIdx.x & 63;
    const int squad = blockIdx.x >> 6;
    const int sbase = squad * SPB;

    // ---- runtime layout probes: true (row, col) of each (lane, reg) ----
    int m_attr[4], n_attr[4];
    {
        half8 ones, enc;
        #pragma unroll
        for (int j = 0; j < 8; ++j) { ones[j] = (_Float16)1.0f; enc[j] = (_Float16)(float)l15; }
        float4a z = {0.f, 0.f, 0.f, 0.f};
        float4a pr = __builtin_amdgcn_mfma_f32_16x16x32_f16(enc, ones, z, 0, 0, 0);
        float4a pc = __builtin_amdgcn_mfma_f32_16x16x32_f16(ones, enc, z, 0, 0, 0);
        #pragma unroll
        for (int r = 0; r < 4; ++r) {
            m_attr[r] = (int)(pr[r] * 0.03125f + 0.5f);   // row feeding this element
            n_attr[r] = (int)(pc[r] * 0.03125f + 0.5f);   // col feeding this element
        }
    }

    // ---- A fragments (regs, whole kernel): wave mq owns rows [mq*64, mq*64+64) ----
    half8 ah[4][4], al[4][4];
    #pragma unroll
    for (int mi = 0; mi < 4; ++mi) {
        int b = mq * 64 + mi * 16 + l15;
        const float* xr = x + (size_t)b * CW + c * E_SZ;
        #pragma unroll
        for (int kk = 0; kk < 4; ++kk) {
            float4a f0 = *reinterpret_cast<const float4a*>(xr + kk * 32 + quad * 8);
            float4a f1 = *reinterpret_cast<const float4a*>(xr + kk * 32 + quad * 8 + 4);
            split8(f0, f1, ah[mi][kk], al[mi][kk]);
        }
    }

    // ---- one-hot zero base ----
    const char* dict_c = reinterpret_cast<const char*>(dict);
    const size_t tile_gbyte0 = ((size_t)c * S_SZ + sbase) * E_SZ * 4;

    // ---- stage tile t into buffer nb via global_load_lds (linear dest,
    //      pre-swizzled per-lane source; wave w covers lds [w*4KB, +4KB)) ----
    auto STAGE = [&](int nb, int t) {
        const char* gb = dict_c + tile_gbyte0 + (size_t)t * (TS * E_SZ * 4);
        char* lb = reinterpret_cast<char*>(&df[nb][0]);
        #pragma unroll
        for (int k = 0; k < 4; ++k) {
            const int off = wid * 4096 + k * 1024 + lane * 16;   // linear lds byte
            const int row = off >> 9;
            const int g   = (off >> 4) & 31;
            const int src = row * 512 + ((g ^ (row & 7)) << 4);
            __builtin_amdgcn_global_load_lds(
                (gu32*)(gb + src),
                (lu32*)(lb + wid * 4096 + k * 1024),   // wave-uniform; HW adds lane*16
                16, 0, 0);
        }
    };

    float bestv[16];
    int   besti[16];
    #pragma unroll
    for (int i = 0; i < 16; ++i) { bestv[i] = 3.4e38f; besti[i] = 0; }

    STAGE(0, 0);
    __syncthreads();   // vmcnt(0): tile 0 resident

    int cur = 0;
    for (int it = 0; it < 16; ++it) {
        // ---- issue next tile's staging (drains by next barrier) ----
        if (it + 1 < 16) STAGE(cur ^ 1, it + 1);

        // ---- zero 16 of the 256 one-hot row-slices (NT, lazy drain) ----
        {
            const int zrow = it * 16 + (tid >> 5);
            const int t5   = tid & 31;
            float* zb = oh + ((size_t)zrow * C_SZ + c) * S_SZ + sbase;
            float4a zz = {0.f, 0.f, 0.f, 0.f};
            #pragma unroll
            for (int j = 0; j < 8; ++j)
                __builtin_nontemporal_store(zz, reinterpret_cast<float4a*>(zb) + t5 + j * 32);
        }

        // ---- consume buf[cur]: ds_read f32 frags + split8 + dp, 96 MFMAs/wave ----
        const char* dfc = reinterpret_cast<const char*>(&df[cur][0]);
        float4a acc[4][2] = {{{0.f,0.f,0.f,0.f},{0.f,0.f,0.f,0.f}},
                             {{0.f,0.f,0.f,0.f},{0.f,0.f,0.f,0.f}},
                             {{0.f,0.f,0.f,0.f},{0.f,0.f,0.f,0.f}},
                             {{0.f,0.f,0.f,0.f},{0.f,0.f,0.f,0.f}}};
        float dp[2] = {0.f, 0.f};
        #pragma unroll
        for (int kk = 0; kk < 4; ++kk) {
            half8 bhf[2], blf[2];
            #pragma unroll
            for (int ni = 0; ni < 2; ++ni) {
                const int sl = nh * 32 + ni * 16 + l15;   // loader believes col = l15
                const int g0 = kk * 8 + quad * 2;
                float4a f0 = *reinterpret_cast<const float4a*>(
                    dfc + sl * 512 + (((g0)     ^ (sl & 7)) << 4));
                float4a f1 = *reinterpret_cast<const float4a*>(
                    dfc + sl * 512 + (((g0 + 1) ^ (sl & 7)) << 4));
                split8(f0, f1, bhf[ni], blf[ni]);
                #pragma unroll
                for (int j = 0; j < 4; ++j) {
                    dp[ni] = fmaf(f0[j], f0[j], dp[ni]);
                    dp[ni] = fmaf(f1[j], f1[j], dp[ni]);
                }
            }
            #pragma unroll
            for (int mi = 0; mi < 4; ++mi)
                #pragma unroll
                for (int ni = 0; ni < 2; ++ni) {
                    acc[mi][ni] = __builtin_amdgcn_mfma_f32_16x16x32_f16(
                        ah[mi][kk], bhf[ni], acc[mi][ni], 0, 0, 0);
                    acc[mi][ni] = __builtin_amdgcn_mfma_f32_16x16x32_f16(
                        ah[mi][kk], blf[ni], acc[mi][ni], 0, 0, 0);
                    acc[mi][ni] = __builtin_amdgcn_mfma_f32_16x16x32_f16(
                        al[mi][kk], bhf[ni], acc[mi][ni], 0, 0, 0);
                }
        }

        // ---- |d|^2 per row: per-quad partial (32 elems) + butterfly ----
        float dsq[2];
        #pragma unroll
        for (int ni = 0; ni < 2; ++ni) {
            float t = dp[ni] + __shfl_xor(dp[ni], 16, 64);
            dsq[ni] = t + __shfl_xor(t, 32, 64);   // row nh*32+ni*16+l15, all quads
        }

        // ---- epilogue: dist = d_sq - 2*cross (x_sq const per (b,c)) ----
        #pragma unroll
        for (int ni = 0; ni < 2; ++ni)
            #pragma unroll
            for (int r = 0; r < 4; ++r) {
                const int na = n_attr[r];                         // true col
                const float dv = __shfl(dsq[ni], (lane & 48) | na, 64);
                const int sg = sbase + it * TS + nh * 32 + ni * 16 + na;
                #pragma unroll
                for (int mi = 0; mi < 4; ++mi) {
                    float dist = dv - 2.0f * acc[mi][ni][r];
                    int slot = mi * 4 + r;
                    if (dist < bestv[slot]) { bestv[slot] = dist; besti[slot] = sg; }
                }
            }

        __syncthreads();   // drains staging loads (+ NT stores) before swap
        cur ^= 1;
    }

    // loop-end barrier: all LDS reads done (alias rv/ri); this block's
    // s-quarter of all 256 one-hot rows is zeroed.

    // ---- dump: bijective (row 0..255) x (col 0..31) scatter, transposed
    //      (rv[col*256+row]) so the scan below is bank-conflict-free ----
    #pragma unroll
    for (int mi = 0; mi < 4; ++mi)
        #pragma unroll
        for (int r = 0; r < 4; ++r) {
            int row = mq * 64 + mi * 16 + m_attr[r];
            int col = nh * 16 + n_attr[r];
            rv[col * 256 + row] = bestv[mi * 4 + r];
            ri[col * 256 + row] = besti[mi * 4 + r];
        }
    __syncthreads();

    if (tid < 256) {
        float bv = 3.4e38f; int bi = 0x7fffffff;
        #pragma unroll 4
        for (int j = 0; j < 32; ++j) {
            float v = rv[j * 256 + tid];
            int   i = ri[j * 256 + tid];
            if (v < bv || (v == bv && i < bi)) { bv = v; bi = i; }  // first-occurrence tie
        }
        // park (dist, idx) in the cw_out cell finalize reads-then-overwrites;
        // squad slots (2 floats each) are disjoint.
        float* cp = cw_out + (size_t)tid * CW + c * E_SZ + squad * 2;
        cp[0] = bv;
        cp[1] = __int_as_float(bi);
    }
    // kernel end drains all NT zero-stores before finalize runs
}

// grid 256 = (btile, c), 256 threads: combine 4 s-quarter candidates per row,
// write the one-hot 1.0, gather cw_embed (overwrites the candidate slab).
__global__ __launch_bounds__(256) void finalize(
    const float* __restrict__ dict,
    float* __restrict__ cw_out,
    float* __restrict__ oh)
{
    __shared__ int fid[64];
    const int c     = blockIdx.x & 63;
    const int btile = blockIdx.x >> 6;
    const int tid   = threadIdx.x;

    if (tid < 64) {
        const int row = btile * 64 + tid;
        const float* cp = cw_out + (size_t)row * CW + c * E_SZ;
        float bv = cp[0]; int bi = __float_as_int(cp[1]);
        #pragma unroll
        for (int k = 1; k < 4; ++k) {
            float v = cp[2 * k];
            // squads are s-ordered: strict < preserves global first-occurrence
            if (v < bv) { bv = v; bi = __float_as_int(cp[2 * k + 1]); }
        }
        fid[tid] = bi;
        oh[((size_t)row * C_SZ + c) * S_SZ + bi] = 1.0f;
    }
    __syncthreads();

    // gather: 64 rows x 32 float4, 4 threads/row x 8 float4 each
    const int row = tid >> 2, q = tid & 3;
    const int bi = fid[row];
    const float4a* src = reinterpret_cast<const float4a*>(
        dict + ((size_t)c * S_SZ + bi) * E_SZ) + q * 8;
    float4a* dst = reinterpret_cast<float4a*>(
        cw_out + (size_t)(btile * 64 + row) * CW + c * E_SZ) + q * 8;
    #pragma unroll
    for (int j = 0; j < 8; ++j) dst[j] = src[j];
}

extern "C" void kernel_launch(void* const* d_in, const int* in_sizes, int n_in,
                              void* d_out, int out_size, void* d_ws, size_t ws_size,
                              hipStream_t stream) {
    const float* x    = (const float*)d_in[0];
    const float* dict = (const float*)d_in[1];
    float* out = (float*)d_out;
    float* oh  = out + (size_t)B_SZ * CW;

    argmin_mfma<<<dim3(256), dim3(512), 0, stream>>>(x, dict, out, oh);
    finalize<<<dim3(256), dim3(256), 0, stream>>>(dict, out, oh);
}